// Round 7
// baseline (212.535 us; speedup 1.0000x reference)
//
#include <hip/hip_runtime.h>
#include <math.h>

typedef unsigned short ushort_t;
typedef unsigned int uint_t;
typedef unsigned long long u64_t;
typedef __attribute__((ext_vector_type(8))) __bf16 bf16x8;
typedef __attribute__((ext_vector_type(4))) float f32x4;

#define NN 4096
#define TT 5
#define F1 32
#define F2 64

__device__ __forceinline__ ushort_t f2bf(float x) {
    union { float f; uint_t u; } v; v.f = x;
    uint_t r = (v.u + 0x7FFFu + ((v.u >> 16) & 1u)) >> 16;
    return (ushort_t)r;
}
__device__ __forceinline__ float bf16f(float x) {
    union { float f; uint_t u; } v; v.f = x;
    v.u = (v.u + 0x7FFFu + ((v.u >> 16) & 1u)) & 0xFFFF0000u;
    return v.f;
}
__device__ __forceinline__ uint_t pk2(float a, float b) {
    return (uint_t)f2bf(a) | ((uint_t)f2bf(b) << 16);
}
__device__ __forceinline__ float tanh_fast(float x) {
    const float xc = fminf(fmaxf(x, -10.f), 10.f);
    const float e = __expf(2.f * xc);
    return (e - 1.f) * __builtin_amdgcn_rcpf(e + 1.f);
}

// ---------------- K0: pack edges -> bits + deg + colbits; 1 wave per row -----------------
// grid 256 x 1024thr (16 waves); per lane 16 int4 (1KB/wave-instr, fully coalesced)
__global__ __launch_bounds__(1024) void k0_pack(
    const int* __restrict__ edges, uint_t* __restrict__ packed,
    int* __restrict__ degI, uint_t* __restrict__ colbits)
{
    const int t = threadIdx.x, w = t >> 6, l = t & 63;
    const int row = blockIdx.x * 16 + w;
    __shared__ u64_t lmask[16][64];   // [wave][lane] 16 nibbles

    const int* ep = edges + (size_t)row * NN + l * 4;
    u64_t nib = 0; int cnt = 0;
    #pragma unroll
    for (int g = 0; g < 2; ++g) {
        int4 v[8];
        #pragma unroll
        for (int q = 0; q < 8; ++q) v[q] = *(const int4*)(ep + (g * 8 + q) * 256);
        #pragma unroll
        for (int q = 0; q < 8; ++q) {
            const uint_t n = (uint_t)(v[q].x != 0) | ((uint_t)(v[q].y != 0) << 1) |
                             ((uint_t)(v[q].z != 0) << 2) | ((uint_t)(v[q].w != 0) << 3);
            cnt += (v[q].x != 0) + (v[q].y != 0) + (v[q].z != 0) + (v[q].w != 0);
            nib |= (u64_t)n << ((g * 8 + q) * 4);
        }
    }
    lmask[w][l] = nib;
    {   // deg: one wave owns the row -> plain store
        int s = cnt;
        #pragma unroll
        for (int off = 32; off >= 1; off >>= 1) s += __shfl_down(s, off, 64);
        if (l == 0) degI[row] = s;
    }
    {   // packed words: lane assembles words l and l+64 (in-wave LDS, lockstep-safe)
        #pragma unroll
        for (int h = 0; h < 2; ++h) {
            const int w2 = l + h * 64;
            const int q = w2 >> 3, g = w2 & 7;
            uint_t word = 0;
            #pragma unroll
            for (int i = 0; i < 8; ++i)
                word |= (uint_t)((lmask[w][g * 8 + i] >> (q * 4)) & 15ull) << (i * 4);
            packed[(size_t)row * 128 + w2] = word;
        }
    }
    __syncthreads();
    if (t < 64) {   // col-OR across the block's 16 rows (thread t touches only [.][t])
        u64_t m = 0;
        #pragma unroll
        for (int w2 = 0; w2 < 16; ++w2) m |= lmask[w2][t];
        lmask[0][t] = m;
    }
    __syncthreads();
    if (t < 128) {
        const int q = t >> 3, g = t & 7;
        uint_t word = 0;
        #pragma unroll
        for (int i = 0; i < 8; ++i)
            word |= (uint_t)((lmask[0][g * 8 + i] >> (q * 4)) & 15ull) << (i * 4);
        atomicOr(&colbits[t], word);
    }
}

// ---------------- K1: conv1 (VALU) + conv2 (MFMA); 512 thr -------------------------------
#define H1S 104
#define CBS 80
__global__ __launch_bounds__(512) void k1_cond(
    const float* __restrict__ ts, const float* __restrict__ Wc1, const float* __restrict__ bc1,
    const float* __restrict__ Wc2, const float* __restrict__ bc2,
    float* __restrict__ condf, ushort_t* __restrict__ condT)
{
    const int b = blockIdx.y;
    const int j0 = blockIdx.x * 64;
    const int t = threadIdx.x;

    __shared__ float sWc1[384];
    __shared__ float sbc1[F1];
    __shared__ float sbc2[F2];
    __shared__ ushort_t sWc2T[64 * H1S];
    __shared__ ushort_t h1B[64 * H1S];
    __shared__ ushort_t scb[64 * CBS];

    for (int i = t; i < 384; i += 512) sWc1[i] = Wc1[i];
    if (t < F1) sbc1[t] = bc1[t];
    if (t < F2) sbc2[t] = bc2[t];
    for (int i = t; i < 96 * 64; i += 512) {
        const int e = i >> 6, f = i & 63;
        sWc2T[f * H1S + e] = f2bf(Wc2[i]);
    }
    __syncthreads();

    {   // phase A: h1 = relu(conv1)
        const int n = t & 63, g = t >> 6;
        const int j = j0 + n;
        float4 x[5];
        #pragma unroll
        for (int tt = 0; tt < 5; ++tt)
            x[tt] = *(const float4*)(ts + ((((size_t)b * TT + tt) << 12) + j) * 4);
        #pragma unroll
        for (int q = 0; q < 12; ++q) {
            const int e = g * 12 + q;
            const int tt0 = e >> 5, f1 = e & 31;
            float a = sbc1[f1];
            #pragma unroll
            for (int dt = 0; dt < 3; ++dt) {
                const float4 xx = x[tt0 + dt];
                a += xx.x * sWc1[(dt * 4 + 0) * F1 + f1];
                a += xx.y * sWc1[(dt * 4 + 1) * F1 + f1];
                a += xx.z * sWc1[(dt * 4 + 2) * F1 + f1];
                a += xx.w * sWc1[(dt * 4 + 3) * F1 + f1];
            }
            h1B[n * H1S + e] = f2bf(fmaxf(a, 0.f));
        }
    }
    __syncthreads();

    {   // phase B: cond = h1 @ Wc2 + bc2 via MFMA; wave -> 16 rows x 32 cols
        const int w = t >> 6, l = t & 63;
        const int m0 = (w & 3) * 16, cH = (w >> 2) * 32;
        const int kseg = (l >> 4) * 8;
        f32x4 acc[2] = {};
        #pragma unroll
        for (int ks = 0; ks < 3; ++ks) {
            const bf16x8 av = *(const bf16x8*)&h1B[(m0 + (l & 15)) * H1S + ks * 32 + kseg];
            #pragma unroll
            for (int ct = 0; ct < 2; ++ct) {
                const bf16x8 bv = *(const bf16x8*)&sWc2T[(cH + ct * 16 + (l & 15)) * H1S + ks * 32 + kseg];
                acc[ct] = __builtin_amdgcn_mfma_f32_16x16x32_bf16(av, bv, acc[ct], 0, 0, 0);
            }
        }
        #pragma unroll
        for (int ct = 0; ct < 2; ++ct)
            #pragma unroll
            for (int i = 0; i < 4; ++i) {
                const int row = m0 + (l >> 4) * 4 + i;
                const int col = cH + ct * 16 + (l & 15);
                const float c = acc[ct][i] + sbc2[col];
                condf[((((size_t)b << 12) + j0 + row) << 6) + col] = c;
                scb[col * CBS + row] = f2bf(c);
            }
    }
    __syncthreads();
    {   // condT writeback: 16B/thread
        const int f2 = t >> 3, seg = t & 7;
        ushort_t* dst = condT + (((size_t)b * 64 + f2) << 12) + j0 + seg * 8;
        *(uint4*)dst = *(const uint4*)&scb[f2 * CBS + seg * 8];
    }
}

// ---------------- K3: packed-A GEMM; 128r x 256c x K512; grid 256 (rt x 8 ksplit) --------
// A expand: XOR-swizzled LDS (bank=(kf^row)&7 conflict-free both sides); B direct from
// per-XCD-L2-resident condT slice (ksplit == blockIdx&7 == XCD on round-robin dispatch).
__global__ __launch_bounds__(1024) void k3_gemm(
    const uint_t* __restrict__ packed, const ushort_t* __restrict__ condT,
    float* __restrict__ aggAll)
{
    const int t = threadIdx.x;
    const int rt = blockIdx.x >> 3, ks = blockIdx.x & 7;
    const int j0 = rt * 128, kb = ks * 512;

    __shared__ __align__(16) ushort_t abuf[2][128 * 16 * 8];   // 2 x 32KB

    // staging role: row = t>>3 (0..127), koct = t&7 -> 16 k-bits = frags koct*2, koct*2+1
    const int srow = t >> 3, koct = t & 7;
    const uint_t* prow = packed + (size_t)(j0 + srow) * 128 + (kb >> 5);
    const int sh = (koct & 1) * 16;
    const int kf0 = koct * 2;
    const int u0 = (srow * 16 + (kf0 ^ (srow & 15))) * 8;
    const int u1 = (srow * 16 + ((kf0 + 1) ^ (srow & 15))) * 8;

    // compute role: wave w: rows (w&7)*16.., cols (w>>3)*128..
    const int w = t >> 6, l = t & 63;
    const int rg = w & 7, chh = w >> 3;
    const int arow = rg * 16 + (l & 15);
    const int asub = l >> 4;
    const ushort_t* bpbase = condT + (size_t)(chh * 128 + (l & 15)) * NN + kb + asub * 8;

    f32x4 acc[8] = {};

    // prologue: stage chunk 0
    {
        const uint_t b16 = prow[koct >> 1] >> sh;
        uint_t e[8];
        #pragma unroll
        for (int p = 0; p < 8; ++p)
            e[p] = (((b16 >> (2 * p)) & 1u) ? 0x3F80u : 0u) |
                   (((b16 >> (2 * p + 1)) & 1u) ? 0x3F800000u : 0u);
        *(uint4*)(&abuf[0][u0]) = make_uint4(e[0], e[1], e[2], e[3]);
        *(uint4*)(&abuf[0][u1]) = make_uint4(e[4], e[5], e[6], e[7]);
    }
    __syncthreads();

    for (int c = 0; c < 4; ++c) {
        uint_t wn = 0;
        if (c < 3) wn = prow[(c + 1) * 4 + (koct >> 1)];   // in flight during compute
        const ushort_t* ab = &abuf[c & 1][0];
        #pragma unroll
        for (int tt = 0; tt < 4; ++tt) {
            const int kf = tt * 4 + asub;
            const bf16x8 av = *(const bf16x8*)(ab + (arow * 16 + (kf ^ (arow & 15))) * 8);
            const ushort_t* bp = bpbase + c * 128 + tt * 32;
            #pragma unroll
            for (int cf = 0; cf < 8; ++cf) {
                const bf16x8 bv = *(const bf16x8*)(bp + (size_t)cf * 16 * NN);
                acc[cf] = __builtin_amdgcn_mfma_f32_16x16x32_bf16(av, bv, acc[cf], 0, 0, 0);
            }
        }
        __syncthreads();
        if (c < 3) {
            const uint_t b16 = wn >> sh;
            uint_t e[8];
            #pragma unroll
            for (int p = 0; p < 8; ++p)
                e[p] = (((b16 >> (2 * p)) & 1u) ? 0x3F80u : 0u) |
                       (((b16 >> (2 * p + 1)) & 1u) ? 0x3F800000u : 0u);
            ushort_t* bufn = &abuf[(c + 1) & 1][0];
            *(uint4*)(bufn + u0) = make_uint4(e[0], e[1], e[2], e[3]);
            *(uint4*)(bufn + u1) = make_uint4(e[4], e[5], e[6], e[7]);
            __syncthreads();
        }
    }

    // epilogue: plain stores to slab ks
    float* slab = aggAll + (size_t)ks * (1 << 20);
    #pragma unroll
    for (int cf = 0; cf < 8; ++cf) {
        const int col = chh * 128 + cf * 16 + (l & 15);
        float* dst = slab + ((size_t)(col >> 6) * NN << 6) + (col & 63);
        #pragma unroll
        for (int i = 0; i < 4; ++i) {
            const int j = j0 + rg * 16 + asub * 4 + i;
            dst[(size_t)j << 6] = acc[cf][i];
        }
    }
}

// ---------------- K4: MLP epilogue on MFMA; sums 8 slabs ---------------------------------
#define WGS 88
#define WDS 136
#define HS  69
__global__ __launch_bounds__(512) void k4_mlp(
    const float* __restrict__ ts, const int* __restrict__ edges,
    const float* __restrict__ condf, const float* __restrict__ aggAll,
    const int* __restrict__ degI, const uint_t* __restrict__ colbits,
    const float* __restrict__ Wg1, const float* __restrict__ bg,
    const float* __restrict__ Wd, const float* __restrict__ bd,
    const float* __restrict__ Wo, const float* __restrict__ bo,
    float* __restrict__ out)
{
    const int b = blockIdx.y;
    const int j0 = blockIdx.x * 64;
    const int t = threadIdx.x;

    __shared__ ushort_t sWg1T[64 * WGS];
    __shared__ ushort_t sWdT[64 * WDS];
    __shared__ ushort_t aggB[64 * WGS];
    __shared__ ushort_t catB[64 * WDS];
    __shared__ float sH[64 * HS];
    __shared__ float sWo[256];
    __shared__ float sbg[64], sbd[64], sbo[4], sAlive[64];

    for (int i = t; i < 4096; i += 512) {
        const int in = i >> 6, o = i & 63;
        sWg1T[o * WGS + in] = f2bf(Wg1[i]);
    }
    for (int i = t; i < 8192; i += 512) {
        const int in = i >> 6, o = i & 63;
        sWdT[o * WDS + in] = f2bf(Wd[i]);
    }
    if (t < 256) sWo[t] = Wo[t];
    if (t >= 256 && t < 320) { sbg[t - 256] = bg[t - 256]; sbd[t - 256] = bd[t - 256]; }
    if (t >= 320 && t < 324) sbo[t - 320] = bo[t - 320];
    if (t >= 384 && t < 448) {
        const int j = j0 + t - 384;
        sAlive[t - 384] = (float)((colbits[j >> 5] >> (j & 31)) & 1u);
    }
    {   // phase 0: aggN = (sum 8 slabs - diag*bf16(cond))/deg -> bf16; cond -> bf16
        const int r = t >> 3, fs = t & 7;
        const int j = j0 + r;
        const float dv = (float)degI[j];
        const float inv = 1.f / (dv > 0.f ? dv : 1.f);
        const float dgf = edges[(size_t)j * NN + j] ? 1.f : 0.f;
        const size_t base = (((size_t)b << 12) + j) << 6;
        #pragma unroll
        for (int q = 0; q < 2; ++q) {
            const int f = fs * 8 + q * 4;
            float4 a4 = {0.f, 0.f, 0.f, 0.f};
            #pragma unroll
            for (int s = 0; s < 8; ++s) {
                const float4 sv = *(const float4*)(aggAll + (size_t)s * (1 << 20) + base + f);
                a4.x += sv.x; a4.y += sv.y; a4.z += sv.z; a4.w += sv.w;
            }
            const float4 c4 = *(const float4*)(condf + base + f);
            const float n0 = (a4.x - dgf * bf16f(c4.x)) * inv;
            const float n1 = (a4.y - dgf * bf16f(c4.y)) * inv;
            const float n2 = (a4.z - dgf * bf16f(c4.z)) * inv;
            const float n3 = (a4.w - dgf * bf16f(c4.w)) * inv;
            *(uint2*)&aggB[r * WGS + f] = make_uint2(pk2(n0, n1), pk2(n2, n3));
            *(uint2*)&catB[r * WDS + f] = make_uint2(pk2(c4.x, c4.y), pk2(c4.z, c4.w));
        }
    }
    __syncthreads();

    const int w = t >> 6, l = t & 63;
    const int m0 = (w & 3) * 16, cH = (w >> 2) * 32;
    const int kseg = (l >> 4) * 8;

    {   // phase G
        f32x4 acc[2] = {};
        #pragma unroll
        for (int ks = 0; ks < 2; ++ks) {
            const bf16x8 av = *(const bf16x8*)&aggB[(m0 + (l & 15)) * WGS + ks * 32 + kseg];
            #pragma unroll
            for (int ct = 0; ct < 2; ++ct) {
                const bf16x8 bv = *(const bf16x8*)&sWg1T[(cH + ct * 16 + (l & 15)) * WGS + ks * 32 + kseg];
                acc[ct] = __builtin_amdgcn_mfma_f32_16x16x32_bf16(av, bv, acc[ct], 0, 0, 0);
            }
        }
        #pragma unroll
        for (int ct = 0; ct < 2; ++ct)
            #pragma unroll
            for (int i = 0; i < 4; ++i) {
                const int row = m0 + (l >> 4) * 4 + i;
                const int col = cH + ct * 16 + (l & 15);
                const float g = tanh_fast(acc[ct][i] + sbg[col]) * sAlive[row];
                catB[row * WDS + 64 + col] = f2bf(g);
            }
    }
    __syncthreads();
    {   // phase H
        f32x4 acc[2] = {};
        #pragma unroll
        for (int ks = 0; ks < 4; ++ks) {
            const bf16x8 av = *(const bf16x8*)&catB[(m0 + (l & 15)) * WDS + ks * 32 + kseg];
            #pragma unroll
            for (int ct = 0; ct < 2; ++ct) {
                const bf16x8 bv = *(const bf16x8*)&sWdT[(cH + ct * 16 + (l & 15)) * WDS + ks * 32 + kseg];
                acc[ct] = __builtin_amdgcn_mfma_f32_16x16x32_bf16(av, bv, acc[ct], 0, 0, 0);
            }
        }
        #pragma unroll
        for (int ct = 0; ct < 2; ++ct)
            #pragma unroll
            for (int i = 0; i < 4; ++i) {
                const int row = m0 + (l >> 4) * 4 + i;
                const int col = cH + ct * 16 + (l & 15);
                sH[row * HS + col] = fmaxf(acc[ct][i] + sbd[col], 0.f);
            }
    }
    __syncthreads();
    if (t < 256) {   // phase O
        const int r = t >> 2, d = t & 3;
        const int j = j0 + r;
        float s = sbo[d];
        #pragma unroll 8
        for (int f = 0; f < 64; ++f) s += sH[r * HS + f] * sWo[f * 4 + d];
        const float segl = ts[((((size_t)b * TT + 4) << 12) + j) * 4 + d];
        out[((((size_t)b << 12) + j) << 2) + d] = segl + tanh_fast(s);
    }
}

// ---------------- launcher ----------------------------------------------------------------
extern "C" void kernel_launch(void* const* d_in, const int* in_sizes, int n_in,
                              void* d_out, int out_size, void* d_ws, size_t ws_size,
                              hipStream_t stream)
{
    (void)in_sizes; (void)n_in; (void)out_size; (void)ws_size;
    const float* ts    = (const float*)d_in[0];
    const int*   edges = (const int*)d_in[1];
    const float* Wc1   = (const float*)d_in[2];
    const float* bc1   = (const float*)d_in[3];
    const float* Wc2   = (const float*)d_in[4];
    const float* bc2   = (const float*)d_in[5];
    const float* Wg1   = (const float*)d_in[6];
    const float* bg    = (const float*)d_in[7];
    const float* Wd    = (const float*)d_in[8];
    const float* bd    = (const float*)d_in[9];
    const float* Wo    = (const float*)d_in[10];
    const float* bo    = (const float*)d_in[11];
    float* out = (float*)d_out;

    char* ws = (char*)d_ws;
    ushort_t* condT   = (ushort_t*)(ws);                            // 2 MiB
    float*    condf   = (float*)(ws + (size_t)(2 << 20));           // 4 MiB
    float*    aggAll  = (float*)(ws + (size_t)(6 << 20));           // 32 MiB (8 slabs)
    uint_t*   packed  = (uint_t*)(ws + (size_t)(38 << 20));         // 2 MiB
    int*      degI    = (int*)(ws + (size_t)(40 << 20));            // 16 KiB
    uint_t*   colbits = (uint_t*)(ws + (size_t)(40 << 20) + 16384); // 512 B

    hipMemsetAsync(colbits, 0, 512, stream);

    k0_pack<<<256, 1024, 0, stream>>>(edges, packed, degI, colbits);
    k1_cond<<<dim3(64, 4), 512, 0, stream>>>(ts, Wc1, bc1, Wc2, bc2, condf, condT);
    k3_gemm<<<256, 1024, 0, stream>>>(packed, condT, aggAll);
    k4_mlp<<<dim3(64, 4), 512, 0, stream>>>(ts, edges, condf, aggAll, degI, colbits,
                                            Wg1, bg, Wd, bd, Wo, bo, out);
}

// Round 8
// 187.792 us; speedup vs baseline: 1.1318x; 1.1318x over previous
//
#include <hip/hip_runtime.h>
#include <math.h>

typedef unsigned short ushort_t;
typedef unsigned int uint_t;
typedef unsigned long long u64_t;
typedef __attribute__((ext_vector_type(8))) __bf16 bf16x8;
typedef __attribute__((ext_vector_type(4))) float f32x4;

#define NN 4096
#define TT 5
#define F1 32
#define F2 64

__device__ __forceinline__ ushort_t f2bf(float x) {
    union { float f; uint_t u; } v; v.f = x;
    uint_t r = (v.u + 0x7FFFu + ((v.u >> 16) & 1u)) >> 16;
    return (ushort_t)r;
}
__device__ __forceinline__ float bf16f(float x) {
    union { float f; uint_t u; } v; v.f = x;
    v.u = (v.u + 0x7FFFu + ((v.u >> 16) & 1u)) & 0xFFFF0000u;
    return v.f;
}
__device__ __forceinline__ uint_t pk2(float a, float b) {
    return (uint_t)f2bf(a) | ((uint_t)f2bf(b) << 16);
}
__device__ __forceinline__ float tanh_fast(float x) {
    const float xc = fminf(fmaxf(x, -10.f), 10.f);
    const float e = __expf(2.f * xc);
    return (e - 1.f) * __builtin_amdgcn_rcpf(e + 1.f);
}
// barrier that waits LDS only (lgkmcnt 0) and leaves global loads in flight
__device__ __forceinline__ void lds_barrier() {
    asm volatile("s_waitcnt lgkmcnt(0)\n\ts_barrier" ::: "memory");
}

// ---------------- K0: pack edges -> bits + deg + colpart; 1 wave per row -----------------
// grid 256 x 1024thr (16 waves); per lane 16 int4 (1KB/wave-instr, fully coalesced)
__global__ __launch_bounds__(1024) void k0_pack(
    const int* __restrict__ edges, uint_t* __restrict__ packed,
    int* __restrict__ degI, uint_t* __restrict__ colpart)
{
    const int t = threadIdx.x, w = t >> 6, l = t & 63;
    const int row = blockIdx.x * 16 + w;
    __shared__ u64_t lmask[16][64];   // [wave][lane] 16 nibbles

    const int* ep = edges + (size_t)row * NN + l * 4;
    u64_t nib = 0; int cnt = 0;
    #pragma unroll
    for (int g = 0; g < 2; ++g) {
        int4 v[8];
        #pragma unroll
        for (int q = 0; q < 8; ++q) v[q] = *(const int4*)(ep + (g * 8 + q) * 256);
        #pragma unroll
        for (int q = 0; q < 8; ++q) {
            const uint_t n = (uint_t)(v[q].x != 0) | ((uint_t)(v[q].y != 0) << 1) |
                             ((uint_t)(v[q].z != 0) << 2) | ((uint_t)(v[q].w != 0) << 3);
            cnt += (v[q].x != 0) + (v[q].y != 0) + (v[q].z != 0) + (v[q].w != 0);
            nib |= (u64_t)n << ((g * 8 + q) * 4);
        }
    }
    lmask[w][l] = nib;
    {   // deg: one wave owns the row -> plain store
        int s = cnt;
        #pragma unroll
        for (int off = 32; off >= 1; off >>= 1) s += __shfl_down(s, off, 64);
        if (l == 0) degI[row] = s;
    }
    {   // packed words: lane assembles words l and l+64 (in-wave LDS, lockstep-safe)
        #pragma unroll
        for (int h = 0; h < 2; ++h) {
            const int w2 = l + h * 64;
            const int q = w2 >> 3, g = w2 & 7;
            uint_t word = 0;
            #pragma unroll
            for (int i = 0; i < 8; ++i)
                word |= (uint_t)((lmask[w][g * 8 + i] >> (q * 4)) & 15ull) << (i * 4);
            packed[(size_t)row * 128 + w2] = word;
        }
    }
    __syncthreads();
    if (t < 64) {   // col-OR across the block's 16 rows
        u64_t m = 0;
        #pragma unroll
        for (int w2 = 0; w2 < 16; ++w2) m |= lmask[w2][t];
        lmask[0][t] = m;
    }
    __syncthreads();
    if (t < 128) {  // per-block partial colbits: plain store, no atomics
        const int q = t >> 3, g = t & 7;
        uint_t word = 0;
        #pragma unroll
        for (int i = 0; i < 8; ++i)
            word |= (uint_t)((lmask[0][g * 8 + i] >> (q * 4)) & 15ull) << (i * 4);
        colpart[(size_t)blockIdx.x * 128 + t] = word;
    }
}

// ---------------- K1: conv1 (VALU) + conv2 (MFMA); 512 thr -------------------------------
#define H1S 104
#define CBS 80
__global__ __launch_bounds__(512) void k1_cond(
    const float* __restrict__ ts, const float* __restrict__ Wc1, const float* __restrict__ bc1,
    const float* __restrict__ Wc2, const float* __restrict__ bc2,
    float* __restrict__ condf, ushort_t* __restrict__ condT)
{
    const int b = blockIdx.y;
    const int j0 = blockIdx.x * 64;
    const int t = threadIdx.x;

    __shared__ float sWc1[384];
    __shared__ float sbc1[F1];
    __shared__ float sbc2[F2];
    __shared__ ushort_t sWc2T[64 * H1S];
    __shared__ ushort_t h1B[64 * H1S];
    __shared__ ushort_t scb[64 * CBS];

    for (int i = t; i < 384; i += 512) sWc1[i] = Wc1[i];
    if (t < F1) sbc1[t] = bc1[t];
    if (t < F2) sbc2[t] = bc2[t];
    for (int i = t; i < 96 * 64; i += 512) {
        const int e = i >> 6, f = i & 63;
        sWc2T[f * H1S + e] = f2bf(Wc2[i]);
    }
    __syncthreads();

    {   // phase A: h1 = relu(conv1)
        const int n = t & 63, g = t >> 6;
        const int j = j0 + n;
        float4 x[5];
        #pragma unroll
        for (int tt = 0; tt < 5; ++tt)
            x[tt] = *(const float4*)(ts + ((((size_t)b * TT + tt) << 12) + j) * 4);
        #pragma unroll
        for (int q = 0; q < 12; ++q) {
            const int e = g * 12 + q;
            const int tt0 = e >> 5, f1 = e & 31;
            float a = sbc1[f1];
            #pragma unroll
            for (int dt = 0; dt < 3; ++dt) {
                const float4 xx = x[tt0 + dt];
                a += xx.x * sWc1[(dt * 4 + 0) * F1 + f1];
                a += xx.y * sWc1[(dt * 4 + 1) * F1 + f1];
                a += xx.z * sWc1[(dt * 4 + 2) * F1 + f1];
                a += xx.w * sWc1[(dt * 4 + 3) * F1 + f1];
            }
            h1B[n * H1S + e] = f2bf(fmaxf(a, 0.f));
        }
    }
    __syncthreads();

    {   // phase B: cond = h1 @ Wc2 + bc2 via MFMA; wave -> 16 rows x 32 cols
        const int w = t >> 6, l = t & 63;
        const int m0 = (w & 3) * 16, cH = (w >> 2) * 32;
        const int kseg = (l >> 4) * 8;
        f32x4 acc[2] = {};
        #pragma unroll
        for (int ks = 0; ks < 3; ++ks) {
            const bf16x8 av = *(const bf16x8*)&h1B[(m0 + (l & 15)) * H1S + ks * 32 + kseg];
            #pragma unroll
            for (int ct = 0; ct < 2; ++ct) {
                const bf16x8 bv = *(const bf16x8*)&sWc2T[(cH + ct * 16 + (l & 15)) * H1S + ks * 32 + kseg];
                acc[ct] = __builtin_amdgcn_mfma_f32_16x16x32_bf16(av, bv, acc[ct], 0, 0, 0);
            }
        }
        #pragma unroll
        for (int ct = 0; ct < 2; ++ct)
            #pragma unroll
            for (int i = 0; i < 4; ++i) {
                const int row = m0 + (l >> 4) * 4 + i;
                const int col = cH + ct * 16 + (l & 15);
                const float c = acc[ct][i] + sbc2[col];
                condf[((((size_t)b << 12) + j0 + row) << 6) + col] = c;
                scb[col * CBS + row] = f2bf(c);
            }
    }
    __syncthreads();
    {   // condT writeback: 16B/thread
        const int f2 = t >> 3, seg = t & 7;
        ushort_t* dst = condT + (((size_t)b * 64 + f2) << 12) + j0 + seg * 8;
        *(uint4*)dst = *(const uint4*)&scb[f2 * CBS + seg * 8];
    }
}

// ---------------- K3: packed-A x condT GEMM, m93-style LDS-staged both operands ----------
// grid 512 = 64 rowtiles(64r) x 2 colhalves(128c) x 4 ksplits(K=1024); 512thr, 8 waves.
// blockIdx = rt*8 + ch*4 + ks -> same B-slice blocks land on one XCD (L2 locality).
// Per BK=128: A 16KB + B 32KB XOR-swizzled LDS; inner loop = ds_read_b128 + MFMA only;
// next chunk's globals prefetched to regs before the lgkmcnt-only barrier.
__global__ __launch_bounds__(512, 4) void k3_gemm(
    const uint_t* __restrict__ packed, const ushort_t* __restrict__ condT,
    float* __restrict__ aggAll)
{
    const int t = threadIdx.x;
    const int rt = blockIdx.x >> 3;
    const int ch = (blockIdx.x >> 2) & 1;
    const int ks = blockIdx.x & 3;
    const int j0 = rt * 64, cb = ch * 128, kb = ks * 1024;

    __shared__ __align__(16) ushort_t aA[64 * 128];   // 16 KB, [row][slot(kf^row&15)*8]
    __shared__ __align__(16) ushort_t bB[128 * 128];  // 32 KB, [col][slot(kf^col&15)*8]

    const int w = t >> 6, l = t & 63;
    // staging roles
    const int arow_s = t >> 3, koct = t & 7;
    const uint_t* prow = packed + (size_t)(j0 + arow_s) * 128 + (kb >> 5);
    const int sh = (koct & 1) * 16;
    const int kf0 = koct * 2;
    const int ua0 = (arow_s * 16 + (kf0 ^ (arow_s & 15))) * 8;
    const int ua1 = (arow_s * 16 + ((kf0 + 1) ^ (arow_s & 15))) * 8;
    // compute roles: wave tile 32r x 32c
    const int rg = w & 1, cg = w >> 1;
    const int ln = l & 15, asub = l >> 4;

    uint_t pa;
    uint4 pb[4];
    int bcol[4], bseg[4];
    #pragma unroll
    for (int p = 0; p < 4; ++p) {
        const int sid = t + p * 512;
        bcol[p] = sid >> 4; bseg[p] = sid & 15;
    }

    // prefetch chunk 0
    pa = prow[koct >> 1];
    #pragma unroll
    for (int p = 0; p < 4; ++p)
        pb[p] = *(const uint4*)(condT + (size_t)(cb + bcol[p]) * NN + kb + bseg[p] * 8);

    f32x4 acc[2][2] = {};

    for (int c = 0; c < 8; ++c) {
        {   // ds_write staged data from regs
            const uint_t b16 = pa >> sh;
            uint_t e[8];
            #pragma unroll
            for (int p2 = 0; p2 < 8; ++p2)
                e[p2] = (((b16 >> (2 * p2)) & 1u) ? 0x3F80u : 0u) |
                        (((b16 >> (2 * p2 + 1)) & 1u) ? 0x3F800000u : 0u);
            *(uint4*)(&aA[ua0]) = make_uint4(e[0], e[1], e[2], e[3]);
            *(uint4*)(&aA[ua1]) = make_uint4(e[4], e[5], e[6], e[7]);
            #pragma unroll
            for (int p = 0; p < 4; ++p)
                *(uint4*)(&bB[(bcol[p] * 16 + (bseg[p] ^ (bcol[p] & 15))) * 8]) = pb[p];
        }
        if (c < 7) {   // prefetch chunk c+1; stays in flight through compute
            pa = prow[(c + 1) * 4 + (koct >> 1)];
            #pragma unroll
            for (int p = 0; p < 4; ++p)
                pb[p] = *(const uint4*)(condT + (size_t)(cb + bcol[p]) * NN
                                        + kb + (c + 1) * 128 + bseg[p] * 8);
        }
        lds_barrier();
        #pragma unroll
        for (int tt = 0; tt < 4; ++tt) {
            const int kf = tt * 4 + asub;
            const int slot = (kf ^ ln) * 8;
            const bf16x8 a0 = *(const bf16x8*)(&aA[(rg * 32 + ln) * 128 + slot]);
            const bf16x8 a1 = *(const bf16x8*)(&aA[(rg * 32 + 16 + ln) * 128 + slot]);
            const bf16x8 b0 = *(const bf16x8*)(&bB[(cg * 32 + ln) * 128 + slot]);
            const bf16x8 b1 = *(const bf16x8*)(&bB[(cg * 32 + 16 + ln) * 128 + slot]);
            acc[0][0] = __builtin_amdgcn_mfma_f32_16x16x32_bf16(a0, b0, acc[0][0], 0, 0, 0);
            acc[0][1] = __builtin_amdgcn_mfma_f32_16x16x32_bf16(a0, b1, acc[0][1], 0, 0, 0);
            acc[1][0] = __builtin_amdgcn_mfma_f32_16x16x32_bf16(a1, b0, acc[1][0], 0, 0, 0);
            acc[1][1] = __builtin_amdgcn_mfma_f32_16x16x32_bf16(a1, b1, acc[1][1], 0, 0, 0);
        }
        lds_barrier();
    }

    // epilogue: plain stores to slab ks
    float* slab = aggAll + ((size_t)ks << 20);
    #pragma unroll
    for (int rt2 = 0; rt2 < 2; ++rt2)
        #pragma unroll
        for (int ct = 0; ct < 2; ++ct) {
            const int col = cb + cg * 32 + ct * 16 + ln;
            float* dst = slab + ((size_t)(col >> 6) * NN << 6) + (col & 63);
            #pragma unroll
            for (int i = 0; i < 4; ++i) {
                const int j = j0 + rg * 32 + rt2 * 16 + asub * 4 + i;
                dst[(size_t)j << 6] = acc[rt2][ct][i];
            }
        }
}

// ---------------- K4: MLP epilogue on MFMA; sums 4 slabs; colpart OR-reduce --------------
#define WGS 88
#define WDS 136
#define HS  69
__global__ __launch_bounds__(512) void k4_mlp(
    const float* __restrict__ ts, const int* __restrict__ edges,
    const float* __restrict__ condf, const float* __restrict__ aggAll,
    const int* __restrict__ degI, const uint_t* __restrict__ colpart,
    const float* __restrict__ Wg1, const float* __restrict__ bg,
    const float* __restrict__ Wd, const float* __restrict__ bd,
    const float* __restrict__ Wo, const float* __restrict__ bo,
    float* __restrict__ out)
{
    const int b = blockIdx.y;
    const int j0 = blockIdx.x * 64;
    const int t = threadIdx.x;

    __shared__ ushort_t sWg1T[64 * WGS];
    __shared__ ushort_t sWdT[64 * WDS];
    __shared__ ushort_t aggB[64 * WGS];
    __shared__ ushort_t catB[64 * WDS];
    __shared__ float sH[64 * HS];
    __shared__ float sWo[256];
    __shared__ float sbg[64], sbd[64], sbo[4];
    __shared__ uint_t sAw[2];

    if (t < 2) sAw[t] = 0u;
    for (int i = t; i < 4096; i += 512) {
        const int in = i >> 6, o = i & 63;
        sWg1T[o * WGS + in] = f2bf(Wg1[i]);
    }
    for (int i = t; i < 8192; i += 512) {
        const int in = i >> 6, o = i & 63;
        sWdT[o * WDS + in] = f2bf(Wd[i]);
    }
    if (t < 256) sWo[t] = Wo[t];
    if (t >= 256 && t < 320) { sbg[t - 256] = bg[t - 256]; sbd[t - 256] = bd[t - 256]; }
    if (t >= 320 && t < 324) sbo[t - 320] = bo[t - 320];
    __syncthreads();   // covers sAw zeroing before the OR below

    if (t >= 384 && t < 448) {   // alive: OR-reduce k0's 256 partials for this j-range
        const int i = t - 384;
        const int wsel = i >> 5, chunk = i & 31;
        uint_t v = 0;
        #pragma unroll
        for (int q = 0; q < 8; ++q)
            v |= colpart[(size_t)(chunk * 8 + q) * 128 + (j0 >> 5) + wsel];
        atomicOr(&sAw[wsel], v);
    }
    {   // phase 0: aggN = (sum 4 slabs - diag*bf16(cond))/deg -> bf16; cond -> bf16
        const int r = t >> 3, fs = t & 7;
        const int j = j0 + r;
        const float dv = (float)degI[j];
        const float inv = 1.f / (dv > 0.f ? dv : 1.f);
        const float dgf = edges[(size_t)j * NN + j] ? 1.f : 0.f;
        const size_t base = (((size_t)b << 12) + j) << 6;
        #pragma unroll
        for (int q = 0; q < 2; ++q) {
            const int f = fs * 8 + q * 4;
            float4 a4 = {0.f, 0.f, 0.f, 0.f};
            #pragma unroll
            for (int s = 0; s < 4; ++s) {
                const float4 sv = *(const float4*)(aggAll + ((size_t)s << 20) + base + f);
                a4.x += sv.x; a4.y += sv.y; a4.z += sv.z; a4.w += sv.w;
            }
            const float4 c4 = *(const float4*)(condf + base + f);
            const float n0 = (a4.x - dgf * bf16f(c4.x)) * inv;
            const float n1 = (a4.y - dgf * bf16f(c4.y)) * inv;
            const float n2 = (a4.z - dgf * bf16f(c4.z)) * inv;
            const float n3 = (a4.w - dgf * bf16f(c4.w)) * inv;
            *(uint2*)&aggB[r * WGS + f] = make_uint2(pk2(n0, n1), pk2(n2, n3));
            *(uint2*)&catB[r * WDS + f] = make_uint2(pk2(c4.x, c4.y), pk2(c4.z, c4.w));
        }
    }
    __syncthreads();

    const int w = t >> 6, l = t & 63;
    const int m0 = (w & 3) * 16, cH = (w >> 2) * 32;
    const int kseg = (l >> 4) * 8;

    {   // phase G
        f32x4 acc[2] = {};
        #pragma unroll
        for (int ks = 0; ks < 2; ++ks) {
            const bf16x8 av = *(const bf16x8*)&aggB[(m0 + (l & 15)) * WGS + ks * 32 + kseg];
            #pragma unroll
            for (int ct = 0; ct < 2; ++ct) {
                const bf16x8 bv = *(const bf16x8*)&sWg1T[(cH + ct * 16 + (l & 15)) * WGS + ks * 32 + kseg];
                acc[ct] = __builtin_amdgcn_mfma_f32_16x16x32_bf16(av, bv, acc[ct], 0, 0, 0);
            }
        }
        #pragma unroll
        for (int ct = 0; ct < 2; ++ct)
            #pragma unroll
            for (int i = 0; i < 4; ++i) {
                const int row = m0 + (l >> 4) * 4 + i;
                const int col = cH + ct * 16 + (l & 15);
                const float alive = (float)((sAw[row >> 5] >> (row & 31)) & 1u);
                const float g = tanh_fast(acc[ct][i] + sbg[col]) * alive;
                catB[row * WDS + 64 + col] = f2bf(g);
            }
    }
    __syncthreads();
    {   // phase H
        f32x4 acc[2] = {};
        #pragma unroll
        for (int ks = 0; ks < 4; ++ks) {
            const bf16x8 av = *(const bf16x8*)&catB[(m0 + (l & 15)) * WDS + ks * 32 + kseg];
            #pragma unroll
            for (int ct = 0; ct < 2; ++ct) {
                const bf16x8 bv = *(const bf16x8*)&sWdT[(cH + ct * 16 + (l & 15)) * WDS + ks * 32 + kseg];
                acc[ct] = __builtin_amdgcn_mfma_f32_16x16x32_bf16(av, bv, acc[ct], 0, 0, 0);
            }
        }
        #pragma unroll
        for (int ct = 0; ct < 2; ++ct)
            #pragma unroll
            for (int i = 0; i < 4; ++i) {
                const int row = m0 + (l >> 4) * 4 + i;
                const int col = cH + ct * 16 + (l & 15);
                sH[row * HS + col] = fmaxf(acc[ct][i] + sbd[col], 0.f);
            }
    }
    __syncthreads();
    if (t < 256) {   // phase O
        const int r = t >> 2, d = t & 3;
        const int j = j0 + r;
        float s = sbo[d];
        #pragma unroll 8
        for (int f = 0; f < 64; ++f) s += sH[r * HS + f] * sWo[f * 4 + d];
        const float segl = ts[((((size_t)b * TT + 4) << 12) + j) * 4 + d];
        out[((((size_t)b << 12) + j) << 2) + d] = segl + tanh_fast(s);
    }
}

// ---------------- launcher ----------------------------------------------------------------
extern "C" void kernel_launch(void* const* d_in, const int* in_sizes, int n_in,
                              void* d_out, int out_size, void* d_ws, size_t ws_size,
                              hipStream_t stream)
{
    (void)in_sizes; (void)n_in; (void)out_size; (void)ws_size;
    const float* ts    = (const float*)d_in[0];
    const int*   edges = (const int*)d_in[1];
    const float* Wc1   = (const float*)d_in[2];
    const float* bc1   = (const float*)d_in[3];
    const float* Wc2   = (const float*)d_in[4];
    const float* bc2   = (const float*)d_in[5];
    const float* Wg1   = (const float*)d_in[6];
    const float* bg    = (const float*)d_in[7];
    const float* Wd    = (const float*)d_in[8];
    const float* bd    = (const float*)d_in[9];
    const float* Wo    = (const float*)d_in[10];
    const float* bo    = (const float*)d_in[11];
    float* out = (float*)d_out;

    char* ws = (char*)d_ws;
    ushort_t* condT   = (ushort_t*)(ws);                            // 2 MiB
    float*    condf   = (float*)(ws + (size_t)(2 << 20));           // 4 MiB
    float*    aggAll  = (float*)(ws + (size_t)(6 << 20));           // 16 MiB (4 slabs)
    uint_t*   packed  = (uint_t*)(ws + (size_t)(22 << 20));         // 2 MiB
    int*      degI    = (int*)(ws + (size_t)(24 << 20));            // 16 KiB
    uint_t*   colpart = (uint_t*)(ws + (size_t)(24 << 20) + 16384); // 128 KiB

    k0_pack<<<256, 1024, 0, stream>>>(edges, packed, degI, colpart);
    k1_cond<<<dim3(64, 4), 512, 0, stream>>>(ts, Wc1, bc1, Wc2, bc2, condf, condT);
    k3_gemm<<<512, 512, 0, stream>>>(packed, condT, aggAll);
    k4_mlp<<<dim3(64, 4), 512, 0, stream>>>(ts, edges, condf, aggAll, degI, colpart,
                                            Wg1, bg, Wd, bd, Wo, bo, out);
}

// Round 9
// 186.688 us; speedup vs baseline: 1.1384x; 1.0059x over previous
//
#include <hip/hip_runtime.h>
#include <math.h>

typedef unsigned short ushort_t;
typedef unsigned int uint_t;
typedef unsigned long long u64_t;
typedef __attribute__((ext_vector_type(8))) __bf16 bf16x8;
typedef __attribute__((ext_vector_type(4))) float f32x4;

#define NN 4096
#define TT 5
#define F1 32
#define F2 64

__device__ __forceinline__ ushort_t f2bf(float x) {
    union { float f; uint_t u; } v; v.f = x;
    uint_t r = (v.u + 0x7FFFu + ((v.u >> 16) & 1u)) >> 16;
    return (ushort_t)r;
}
__device__ __forceinline__ float bf16f(float x) {
    union { float f; uint_t u; } v; v.f = x;
    v.u = (v.u + 0x7FFFu + ((v.u >> 16) & 1u)) & 0xFFFF0000u;
    return v.f;
}
__device__ __forceinline__ uint_t pk2(float a, float b) {
    return (uint_t)f2bf(a) | ((uint_t)f2bf(b) << 16);
}
__device__ __forceinline__ float tanh_fast(float x) {
    const float xc = fminf(fmaxf(x, -10.f), 10.f);
    const float e = __expf(2.f * xc);
    return (e - 1.f) * __builtin_amdgcn_rcpf(e + 1.f);
}
// barrier that waits LDS only (lgkmcnt 0) and leaves global loads in flight
__device__ __forceinline__ void lds_barrier() {
    asm volatile("s_waitcnt lgkmcnt(0)\n\ts_barrier" ::: "memory");
}

// ---------------- K0: pack edges -> bits + deg + colpart; 1 wave per row -----------------
__global__ __launch_bounds__(1024) void k0_pack(
    const int* __restrict__ edges, uint_t* __restrict__ packed,
    int* __restrict__ degI, uint_t* __restrict__ colpart)
{
    const int t = threadIdx.x, w = t >> 6, l = t & 63;
    const int row = blockIdx.x * 16 + w;
    __shared__ u64_t lmask[16][64];

    const int* ep = edges + (size_t)row * NN + l * 4;
    u64_t nib = 0; int cnt = 0;
    #pragma unroll
    for (int g = 0; g < 2; ++g) {
        int4 v[8];
        #pragma unroll
        for (int q = 0; q < 8; ++q) v[q] = *(const int4*)(ep + (g * 8 + q) * 256);
        #pragma unroll
        for (int q = 0; q < 8; ++q) {
            const uint_t n = (uint_t)(v[q].x != 0) | ((uint_t)(v[q].y != 0) << 1) |
                             ((uint_t)(v[q].z != 0) << 2) | ((uint_t)(v[q].w != 0) << 3);
            cnt += (v[q].x != 0) + (v[q].y != 0) + (v[q].z != 0) + (v[q].w != 0);
            nib |= (u64_t)n << ((g * 8 + q) * 4);
        }
    }
    lmask[w][l] = nib;
    {
        int s = cnt;
        #pragma unroll
        for (int off = 32; off >= 1; off >>= 1) s += __shfl_down(s, off, 64);
        if (l == 0) degI[row] = s;
    }
    {
        #pragma unroll
        for (int h = 0; h < 2; ++h) {
            const int w2 = l + h * 64;
            const int q = w2 >> 3, g = w2 & 7;
            uint_t word = 0;
            #pragma unroll
            for (int i = 0; i < 8; ++i)
                word |= (uint_t)((lmask[w][g * 8 + i] >> (q * 4)) & 15ull) << (i * 4);
            packed[(size_t)row * 128 + w2] = word;
        }
    }
    __syncthreads();
    if (t < 64) {
        u64_t m = 0;
        #pragma unroll
        for (int w2 = 0; w2 < 16; ++w2) m |= lmask[w2][t];
        lmask[0][t] = m;
    }
    __syncthreads();
    if (t < 128) {
        const int q = t >> 3, g = t & 7;
        uint_t word = 0;
        #pragma unroll
        for (int i = 0; i < 8; ++i)
            word |= (uint_t)((lmask[0][g * 8 + i] >> (q * 4)) & 15ull) << (i * 4);
        colpart[(size_t)blockIdx.x * 128 + t] = word;
    }
}

// ---------------- K1: conv1 (VALU) + conv2 (MFMA); 512 thr -------------------------------
#define H1S 104
#define CBS 80
__global__ __launch_bounds__(512) void k1_cond(
    const float* __restrict__ ts, const float* __restrict__ Wc1, const float* __restrict__ bc1,
    const float* __restrict__ Wc2, const float* __restrict__ bc2,
    float* __restrict__ condf, ushort_t* __restrict__ condT)
{
    const int b = blockIdx.y;
    const int j0 = blockIdx.x * 64;
    const int t = threadIdx.x;

    __shared__ float sWc1[384];
    __shared__ float sbc1[F1];
    __shared__ float sbc2[F2];
    __shared__ ushort_t sWc2T[64 * H1S];
    __shared__ ushort_t h1B[64 * H1S];
    __shared__ ushort_t scb[64 * CBS];

    for (int i = t; i < 384; i += 512) sWc1[i] = Wc1[i];
    if (t < F1) sbc1[t] = bc1[t];
    if (t < F2) sbc2[t] = bc2[t];
    for (int i = t; i < 96 * 64; i += 512) {
        const int e = i >> 6, f = i & 63;
        sWc2T[f * H1S + e] = f2bf(Wc2[i]);
    }
    __syncthreads();

    {   // phase A: h1 = relu(conv1)
        const int n = t & 63, g = t >> 6;
        const int j = j0 + n;
        float4 x[5];
        #pragma unroll
        for (int tt = 0; tt < 5; ++tt)
            x[tt] = *(const float4*)(ts + ((((size_t)b * TT + tt) << 12) + j) * 4);
        #pragma unroll
        for (int q = 0; q < 12; ++q) {
            const int e = g * 12 + q;
            const int tt0 = e >> 5, f1 = e & 31;
            float a = sbc1[f1];
            #pragma unroll
            for (int dt = 0; dt < 3; ++dt) {
                const float4 xx = x[tt0 + dt];
                a += xx.x * sWc1[(dt * 4 + 0) * F1 + f1];
                a += xx.y * sWc1[(dt * 4 + 1) * F1 + f1];
                a += xx.z * sWc1[(dt * 4 + 2) * F1 + f1];
                a += xx.w * sWc1[(dt * 4 + 3) * F1 + f1];
            }
            h1B[n * H1S + e] = f2bf(fmaxf(a, 0.f));
        }
    }
    __syncthreads();

    {   // phase B: cond = h1 @ Wc2 + bc2 via MFMA; wave -> 16 rows x 32 cols
        const int w = t >> 6, l = t & 63;
        const int m0 = (w & 3) * 16, cH = (w >> 2) * 32;
        const int kseg = (l >> 4) * 8;
        f32x4 acc[2] = {};
        #pragma unroll
        for (int ks = 0; ks < 3; ++ks) {
            const bf16x8 av = *(const bf16x8*)&h1B[(m0 + (l & 15)) * H1S + ks * 32 + kseg];
            #pragma unroll
            for (int ct = 0; ct < 2; ++ct) {
                const bf16x8 bv = *(const bf16x8*)&sWc2T[(cH + ct * 16 + (l & 15)) * H1S + ks * 32 + kseg];
                acc[ct] = __builtin_amdgcn_mfma_f32_16x16x32_bf16(av, bv, acc[ct], 0, 0, 0);
            }
        }
        #pragma unroll
        for (int ct = 0; ct < 2; ++ct)
            #pragma unroll
            for (int i = 0; i < 4; ++i) {
                const int row = m0 + (l >> 4) * 4 + i;
                const int col = cH + ct * 16 + (l & 15);
                const float c = acc[ct][i] + sbc2[col];
                condf[((((size_t)b << 12) + j0 + row) << 6) + col] = c;
                scb[col * CBS + row] = f2bf(c);
            }
    }
    __syncthreads();
    {   // condT writeback: 16B/thread
        const int f2 = t >> 3, seg = t & 7;
        ushort_t* dst = condT + (((size_t)b * 64 + f2) << 12) + j0 + seg * 8;
        *(uint4*)dst = *(const uint4*)&scb[f2 * CBS + seg * 8];
    }
}

// ---------------- K3: packed-A x condT GEMM, LDS-staged; COALESCED epilogue --------------
// grid 512 = 64 rowtiles(64r) x 2 colhalves(128c) x 4 ksplits(K=1024); 512thr, 8 waves.
// Epilogue: acc -> LDS transpose (stride 68: 2-way-free banks) -> float4 full-line stores.
__global__ __launch_bounds__(512, 4) void k3_gemm(
    const uint_t* __restrict__ packed, const ushort_t* __restrict__ condT,
    float* __restrict__ aggAll)
{
    const int t = threadIdx.x;
    const int rt = blockIdx.x >> 3;
    const int ch = (blockIdx.x >> 2) & 1;
    const int ks = blockIdx.x & 3;
    const int j0 = rt * 64, kb = ks * 1024;
    const int cb = ch * 128;

    __shared__ __align__(16) ushort_t smem[24576];   // 48 KB
    ushort_t* aA = smem;          // 16 KB, [row][slot(kf^row&15)*8]
    ushort_t* bB = smem + 8192;   // 32 KB, [col][slot(kf^col&15)*8]

    const int w = t >> 6, l = t & 63;
    // staging roles
    const int arow_s = t >> 3, koct = t & 7;
    const uint_t* prow = packed + (size_t)(j0 + arow_s) * 128 + (kb >> 5);
    const int sh = (koct & 1) * 16;
    const int kf0 = koct * 2;
    const int ua0 = (arow_s * 16 + (kf0 ^ (arow_s & 15))) * 8;
    const int ua1 = (arow_s * 16 + ((kf0 + 1) ^ (arow_s & 15))) * 8;
    // compute roles: wave tile 32r x 32c
    const int rg = w & 1, cg = w >> 1;
    const int ln = l & 15, asub = l >> 4;

    uint_t pa;
    uint4 pb[4];
    int bcol[4], bseg[4];
    #pragma unroll
    for (int p = 0; p < 4; ++p) {
        const int sid = t + p * 512;
        bcol[p] = sid >> 4; bseg[p] = sid & 15;
    }

    // prefetch chunk 0
    pa = prow[koct >> 1];
    #pragma unroll
    for (int p = 0; p < 4; ++p)
        pb[p] = *(const uint4*)(condT + (size_t)(cb + bcol[p]) * NN + kb + bseg[p] * 8);

    f32x4 acc[2][2] = {};

    for (int c = 0; c < 8; ++c) {
        {   // ds_write staged data from regs
            const uint_t b16 = pa >> sh;
            uint_t e[8];
            #pragma unroll
            for (int p2 = 0; p2 < 8; ++p2)
                e[p2] = (((b16 >> (2 * p2)) & 1u) ? 0x3F80u : 0u) |
                        (((b16 >> (2 * p2 + 1)) & 1u) ? 0x3F800000u : 0u);
            *(uint4*)(&aA[ua0]) = make_uint4(e[0], e[1], e[2], e[3]);
            *(uint4*)(&aA[ua1]) = make_uint4(e[4], e[5], e[6], e[7]);
            #pragma unroll
            for (int p = 0; p < 4; ++p)
                *(uint4*)(&bB[(bcol[p] * 16 + (bseg[p] ^ (bcol[p] & 15))) * 8]) = pb[p];
        }
        if (c < 7) {   // prefetch chunk c+1; stays in flight through compute
            pa = prow[(c + 1) * 4 + (koct >> 1)];
            #pragma unroll
            for (int p = 0; p < 4; ++p)
                pb[p] = *(const uint4*)(condT + (size_t)(cb + bcol[p]) * NN
                                        + kb + (c + 1) * 128 + bseg[p] * 8);
        }
        lds_barrier();
        #pragma unroll
        for (int tt = 0; tt < 4; ++tt) {
            const int kf = tt * 4 + asub;
            const int slot = (kf ^ ln) * 8;
            const bf16x8 a0 = *(const bf16x8*)(&aA[(rg * 32 + ln) * 128 + slot]);
            const bf16x8 a1 = *(const bf16x8*)(&aA[(rg * 32 + 16 + ln) * 128 + slot]);
            const bf16x8 b0 = *(const bf16x8*)(&bB[(cg * 32 + ln) * 128 + slot]);
            const bf16x8 b1 = *(const bf16x8*)(&bB[(cg * 32 + 16 + ln) * 128 + slot]);
            acc[0][0] = __builtin_amdgcn_mfma_f32_16x16x32_bf16(a0, b0, acc[0][0], 0, 0, 0);
            acc[0][1] = __builtin_amdgcn_mfma_f32_16x16x32_bf16(a0, b1, acc[0][1], 0, 0, 0);
            acc[1][0] = __builtin_amdgcn_mfma_f32_16x16x32_bf16(a1, b0, acc[1][0], 0, 0, 0);
            acc[1][1] = __builtin_amdgcn_mfma_f32_16x16x32_bf16(a1, b1, acc[1][1], 0, 0, 0);
        }
        lds_barrier();
    }

    // ---- coalesced epilogue: LDS transpose then full-line float4 stores ----
    __syncthreads();                     // all MFMA LDS reads done; safe to overwrite smem
    float* eb = (float*)smem;            // [g(2)][jl(64)] rows of 68, 34816 B < 48 KB
    #pragma unroll
    for (int rt2 = 0; rt2 < 2; ++rt2)
        #pragma unroll
        for (int ct = 0; ct < 2; ++ct) {
            const int lc = cg * 32 + ct * 16 + ln;
            const int g = lc >> 6, c64 = lc & 63;
            #pragma unroll
            for (int i = 0; i < 4; ++i) {
                const int jl = rg * 32 + rt2 * 16 + asub * 4 + i;
                eb[(g * 64 + jl) * 68 + c64] = acc[rt2][ct][i];
            }
        }
    __syncthreads();
    float* slab = aggAll + ((size_t)ks << 20);
    #pragma unroll
    for (int r2 = 0; r2 < 4; ++r2) {
        const int q = r2 * 2048 + t * 4;
        const int g = q >> 12, jl = (q >> 6) & 63, c64 = q & 63;
        const float4 v = *(const float4*)&eb[(g * 64 + jl) * 68 + c64];
        *(float4*)(slab + (((size_t)(2 * ch + g) * NN + j0 + jl) << 6) + c64) = v;
    }
}

// ---------------- K4: MLP epilogue on MFMA; sums 4 slabs; colpart OR-reduce --------------
#define WGS 88
#define WDS 136
#define HS  69
__global__ __launch_bounds__(512) void k4_mlp(
    const float* __restrict__ ts, const int* __restrict__ edges,
    const float* __restrict__ condf, const float* __restrict__ aggAll,
    const int* __restrict__ degI, const uint_t* __restrict__ colpart,
    const float* __restrict__ Wg1, const float* __restrict__ bg,
    const float* __restrict__ Wd, const float* __restrict__ bd,
    const float* __restrict__ Wo, const float* __restrict__ bo,
    float* __restrict__ out)
{
    const int b = blockIdx.y;
    const int j0 = blockIdx.x * 64;
    const int t = threadIdx.x;

    __shared__ ushort_t sWg1T[64 * WGS];
    __shared__ ushort_t sWdT[64 * WDS];
    __shared__ ushort_t aggB[64 * WGS];
    __shared__ ushort_t catB[64 * WDS];
    __shared__ float sH[64 * HS];
    __shared__ float sWo[256];
    __shared__ float sbg[64], sbd[64], sbo[4];
    __shared__ uint_t sAw[2];

    if (t < 2) sAw[t] = 0u;
    for (int i = t; i < 4096; i += 512) {
        const int in = i >> 6, o = i & 63;
        sWg1T[o * WGS + in] = f2bf(Wg1[i]);
    }
    for (int i = t; i < 8192; i += 512) {
        const int in = i >> 6, o = i & 63;
        sWdT[o * WDS + in] = f2bf(Wd[i]);
    }
    if (t < 256) sWo[t] = Wo[t];
    if (t >= 256 && t < 320) { sbg[t - 256] = bg[t - 256]; sbd[t - 256] = bd[t - 256]; }
    if (t >= 320 && t < 324) sbo[t - 320] = bo[t - 320];
    __syncthreads();   // covers sAw zeroing before the OR below

    if (t >= 384 && t < 448) {   // alive: OR-reduce k0's 256 partials for this j-range
        const int i = t - 384;
        const int wsel = i >> 5, chunk = i & 31;
        uint_t v = 0;
        #pragma unroll
        for (int q = 0; q < 8; ++q)
            v |= colpart[(size_t)(chunk * 8 + q) * 128 + (j0 >> 5) + wsel];
        atomicOr(&sAw[wsel], v);
    }
    {   // phase 0: aggN = (sum 4 slabs - diag*bf16(cond))/deg -> bf16; cond -> bf16
        const int r = t >> 3, fs = t & 7;
        const int j = j0 + r;
        const float dv = (float)degI[j];
        const float inv = 1.f / (dv > 0.f ? dv : 1.f);
        const float dgf = edges[(size_t)j * NN + j] ? 1.f : 0.f;
        const size_t base = (((size_t)b << 12) + j) << 6;
        #pragma unroll
        for (int q = 0; q < 2; ++q) {
            const int f = fs * 8 + q * 4;
            float4 a4 = {0.f, 0.f, 0.f, 0.f};
            #pragma unroll
            for (int s = 0; s < 4; ++s) {
                const float4 sv = *(const float4*)(aggAll + ((size_t)s << 20) + base + f);
                a4.x += sv.x; a4.y += sv.y; a4.z += sv.z; a4.w += sv.w;
            }
            const float4 c4 = *(const float4*)(condf + base + f);
            const float n0 = (a4.x - dgf * bf16f(c4.x)) * inv;
            const float n1 = (a4.y - dgf * bf16f(c4.y)) * inv;
            const float n2 = (a4.z - dgf * bf16f(c4.z)) * inv;
            const float n3 = (a4.w - dgf * bf16f(c4.w)) * inv;
            *(uint2*)&aggB[r * WGS + f] = make_uint2(pk2(n0, n1), pk2(n2, n3));
            *(uint2*)&catB[r * WDS + f] = make_uint2(pk2(c4.x, c4.y), pk2(c4.z, c4.w));
        }
    }
    __syncthreads();

    const int w = t >> 6, l = t & 63;
    const int m0 = (w & 3) * 16, cH = (w >> 2) * 32;
    const int kseg = (l >> 4) * 8;

    {   // phase G
        f32x4 acc[2] = {};
        #pragma unroll
        for (int ks = 0; ks < 2; ++ks) {
            const bf16x8 av = *(const bf16x8*)&aggB[(m0 + (l & 15)) * WGS + ks * 32 + kseg];
            #pragma unroll
            for (int ct = 0; ct < 2; ++ct) {
                const bf16x8 bv = *(const bf16x8*)&sWg1T[(cH + ct * 16 + (l & 15)) * WGS + ks * 32 + kseg];
                acc[ct] = __builtin_amdgcn_mfma_f32_16x16x32_bf16(av, bv, acc[ct], 0, 0, 0);
            }
        }
        #pragma unroll
        for (int ct = 0; ct < 2; ++ct)
            #pragma unroll
            for (int i = 0; i < 4; ++i) {
                const int row = m0 + (l >> 4) * 4 + i;
                const int col = cH + ct * 16 + (l & 15);
                const float alive = (float)((sAw[row >> 5] >> (row & 31)) & 1u);
                const float g = tanh_fast(acc[ct][i] + sbg[col]) * alive;
                catB[row * WDS + 64 + col] = f2bf(g);
            }
    }
    __syncthreads();
    {   // phase H
        f32x4 acc[2] = {};
        #pragma unroll
        for (int ks = 0; ks < 4; ++ks) {
            const bf16x8 av = *(const bf16x8*)&catB[(m0 + (l & 15)) * WDS + ks * 32 + kseg];
            #pragma unroll
            for (int ct = 0; ct < 2; ++ct) {
                const bf16x8 bv = *(const bf16x8*)&sWdT[(cH + ct * 16 + (l & 15)) * WDS + ks * 32 + kseg];
                acc[ct] = __builtin_amdgcn_mfma_f32_16x16x32_bf16(av, bv, acc[ct], 0, 0, 0);
            }
        }
        #pragma unroll
        for (int ct = 0; ct < 2; ++ct)
            #pragma unroll
            for (int i = 0; i < 4; ++i) {
                const int row = m0 + (l >> 4) * 4 + i;
                const int col = cH + ct * 16 + (l & 15);
                sH[row * HS + col] = fmaxf(acc[ct][i] + sbd[col], 0.f);
            }
    }
    __syncthreads();
    if (t < 256) {   // phase O
        const int r = t >> 2, d = t & 3;
        const int j = j0 + r;
        float s = sbo[d];
        #pragma unroll 8
        for (int f = 0; f < 64; ++f) s += sH[r * HS + f] * sWo[f * 4 + d];
        const float segl = ts[((((size_t)b * TT + 4) << 12) + j) * 4 + d];
        out[((((size_t)b << 12) + j) << 2) + d] = segl + tanh_fast(s);
    }
}

// ---------------- launcher ----------------------------------------------------------------
extern "C" void kernel_launch(void* const* d_in, const int* in_sizes, int n_in,
                              void* d_out, int out_size, void* d_ws, size_t ws_size,
                              hipStream_t stream)
{
    (void)in_sizes; (void)n_in; (void)out_size; (void)ws_size;
    const float* ts    = (const float*)d_in[0];
    const int*   edges = (const int*)d_in[1];
    const float* Wc1   = (const float*)d_in[2];
    const float* bc1   = (const float*)d_in[3];
    const float* Wc2   = (const float*)d_in[4];
    const float* bc2   = (const float*)d_in[5];
    const float* Wg1   = (const float*)d_in[6];
    const float* bg    = (const float*)d_in[7];
    const float* Wd    = (const float*)d_in[8];
    const float* bd    = (const float*)d_in[9];
    const float* Wo    = (const float*)d_in[10];
    const float* bo    = (const float*)d_in[11];
    float* out = (float*)d_out;

    char* ws = (char*)d_ws;
    ushort_t* condT   = (ushort_t*)(ws);                            // 2 MiB
    float*    condf   = (float*)(ws + (size_t)(2 << 20));           // 4 MiB
    float*    aggAll  = (float*)(ws + (size_t)(6 << 20));           // 16 MiB (4 slabs)
    uint_t*   packed  = (uint_t*)(ws + (size_t)(22 << 20));         // 2 MiB
    int*      degI    = (int*)(ws + (size_t)(24 << 20));            // 16 KiB
    uint_t*   colpart = (uint_t*)(ws + (size_t)(24 << 20) + 16384); // 128 KiB

    k0_pack<<<256, 1024, 0, stream>>>(edges, packed, degI, colpart);
    k1_cond<<<dim3(64, 4), 512, 0, stream>>>(ts, Wc1, bc1, Wc2, bc2, condf, condT);
    k3_gemm<<<512, 512, 0, stream>>>(packed, condT, aggAll);
    k4_mlp<<<dim3(64, 4), 512, 0, stream>>>(ts, edges, condf, aggAll, degI, colpart,
                                            Wg1, bg, Wd, bd, Wo, bo, out);
}